// Round 1
// baseline (2156.601 us; speedup 1.0000x reference)
//
#include <hip/hip_runtime.h>
#include <hip/hip_bf16.h>

#define T_STEPS 2048
#define BATCH   1024
#define NUNITS  128
#define EMB     24

typedef __attribute__((ext_vector_type(8))) __bf16 bf16x8;
typedef __attribute__((ext_vector_type(4))) float  f32x4;

__device__ __forceinline__ float fast_exp(float x) {
    return __builtin_amdgcn_exp2f(x * 1.4426950408889634f);
}
__device__ __forceinline__ float fast_rcp(float x) {
    return __builtin_amdgcn_rcpf(x);
}
__device__ __forceinline__ float sigm(float x) {
    return fast_rcp(1.0f + fast_exp(-x));
}
__device__ __forceinline__ float tanh_f(float x) {
    float a = fabsf(x);
    float t = fast_exp(-2.0f * a);
    float r = (1.0f - t) * fast_rcp(1.0f + t);
    return copysignf(r, x);
}

// ---------------- embedding pre-pass: e[t][b][j] = sigmoid(x[b][t][:] @ Wemb + bemb), bf16 out
__global__ __launch_bounds__(256) void emb_kernel(const float* __restrict__ x,
                                                  const float* __restrict__ Wemb,
                                                  const float* __restrict__ bemb,
                                                  ushort* __restrict__ e_out) {
    int g = blockIdx.x * 256 + threadIdx.x;   // g = t*1024 + b
    int t = g >> 10;
    int b = g & 1023;
    const float* xr = x + ((size_t)b * T_STEPS + t) * 64;

    float4 xv[16];
#pragma unroll
    for (int i = 0; i < 16; i++) xv[i] = ((const float4*)xr)[i];

    float acc[24];
#pragma unroll
    for (int j = 0; j < 24; j++) acc[j] = bemb[j];

#pragma unroll
    for (int d = 0; d < 64; d++) {
        float xs = ((const float*)xv)[d];
#pragma unroll
        for (int j = 0; j < 24; j++) acc[j] = fmaf(xs, Wemb[d * 24 + j], acc[j]);
    }

    uint outp[12];
#pragma unroll
    for (int p = 0; p < 12; p++) {
        ushort lo = __builtin_bit_cast(ushort, (__bf16)sigm(acc[2 * p]));
        ushort hi = __builtin_bit_cast(ushort, (__bf16)sigm(acc[2 * p + 1]));
        outp[p] = (uint)lo | ((uint)hi << 16);
    }
    uint4* dst = (uint4*)(e_out + (size_t)g * 24);
#pragma unroll
    for (int q = 0; q < 3; q++) dst[q] = ((const uint4*)outp)[q];
}

// ---------------- recurrent kernel: 64 blocks x 512 threads, 16 batch rows per block
__global__ __launch_bounds__(512) void lstm_kernel(
    const ushort* __restrict__ e_ws,
    const float* __restrict__ Wf, const float* __restrict__ bf_,
    const float* __restrict__ Wi, const float* __restrict__ bi_,
    const float* __restrict__ Wg, const float* __restrict__ bg_,
    const float* __restrict__ Wo, const float* __restrict__ bo_,
    const float* __restrict__ Wout, const float* __restrict__ bout,
    float* __restrict__ out) {
    // z layout per row (168 bf16, stride 336B = 21*16B -> uniform bank use on b128 reads):
    //   k in [0,128)   : h
    //   k in [128,152) : e_t
    //   k in [152,160) : zero pad (K padded to 5*32)
    __shared__ __align__(16) __bf16 zbuf[16][168];

    const int tid  = threadIdx.x;
    const int lane = tid & 63;
    const int wv   = tid >> 6;      // wave 0..7
    const int l15  = lane & 15;
    const int kg   = lane >> 4;     // 0..3
    const int r0   = blockIdx.x * 16;

    // ---- load persistent weight B-fragments (bf16) into registers
    const float* Wp[4] = {Wf, Wi, Wg, Wo};
    const int gcol = wv * 16 + l15;     // unit index 0..127 (this wave's 16-col slice)
    bf16x8 bfrag[4][5];
#pragma unroll
    for (int gt = 0; gt < 4; gt++) {
        const float* W = Wp[gt];
#pragma unroll
        for (int ks = 0; ks < 5; ks++) {
#pragma unroll
            for (int j = 0; j < 8; j++) {
                int k = ks * 32 + kg * 8 + j;
                float v = 0.0f;
                if (k < 128) v = W[(24 + k) * NUNITS + gcol];        // h part (ref rows 24..151)
                else if (k < 152) v = W[(k - 128) * NUNITS + gcol];  // e part (ref rows 0..23)
                bfrag[gt][ks][j] = (__bf16)v;
            }
        }
    }
    const float bias0 = bf_[gcol], bias1 = bi_[gcol], bias2 = bg_[gcol], bias3 = bo_[gcol];

    // zero the pad region k in [152,160)
    if (tid < 128) zbuf[tid >> 3][152 + (tid & 7)] = (__bf16)0.0f;

    float c[4] = {0, 0, 0, 0};
    float h[4] = {0, 0, 0, 0};

    // e prefetch (2 bf16 per thread for tid<192 covers 16 rows x 24)
    uint e_reg = 0;
    if (tid < 192) e_reg = *(const uint*)(e_ws + ((size_t)0 * BATCH + r0) * 24 + 2 * tid);

    for (int t = 0; t < T_STEPS; ++t) {
        // write h (this thread holds rows kg*4+r, col gcol) and e_t into z
#pragma unroll
        for (int r = 0; r < 4; r++) zbuf[kg * 4 + r][gcol] = (__bf16)h[r];
        if (tid < 192) {
            int ei = 2 * tid;
            *(uint*)((__bf16*)(&zbuf[0][0]) + (ei / 24) * 168 + 128 + (ei % 24)) = e_reg;
        }
        __syncthreads();

        // prefetch next step's e
        if (tid < 192) {
            int tn = (t + 1 < T_STEPS) ? (t + 1) : t;
            e_reg = *(const uint*)(e_ws + ((size_t)tn * BATCH + r0) * 24 + 2 * tid);
        }

        f32x4 aF = {bias0, bias0, bias0, bias0};
        f32x4 aI = {bias1, bias1, bias1, bias1};
        f32x4 aG = {bias2, bias2, bias2, bias2};
        f32x4 aO = {bias3, bias3, bias3, bias3};
#pragma unroll
        for (int ks = 0; ks < 5; ks++) {
            bf16x8 a = *(const bf16x8*)(&zbuf[l15][ks * 32 + kg * 8]);
            aF = __builtin_amdgcn_mfma_f32_16x16x32_bf16(a, bfrag[0][ks], aF, 0, 0, 0);
            aI = __builtin_amdgcn_mfma_f32_16x16x32_bf16(a, bfrag[1][ks], aI, 0, 0, 0);
            aG = __builtin_amdgcn_mfma_f32_16x16x32_bf16(a, bfrag[2][ks], aG, 0, 0, 0);
            aO = __builtin_amdgcn_mfma_f32_16x16x32_bf16(a, bfrag[3][ks], aO, 0, 0, 0);
        }

#pragma unroll
        for (int r = 0; r < 4; r++) {
            float fg = sigm(aF[r]);
            float ig = sigm(aI[r]);
            float gg = tanh_f(aG[r]);
            float og = sigm(aO[r]);
            c[r] = c[r] * fg + ig * gg;
            h[r] = tanh_f(c[r]) * og;
        }
        __syncthreads();   // all reads of z done before next iter overwrites
    }

    // epilogue: out = sigmoid(h_last @ Wout + bout)
#pragma unroll
    for (int r = 0; r < 4; r++) zbuf[kg * 4 + r][gcol] = (__bf16)h[r];
    __syncthreads();
    if (tid < 16) {
        float s = bout[0];
        for (int k = 0; k < NUNITS; k++) s += (float)zbuf[tid][k] * Wout[k];
        out[r0 + tid] = sigm(s);
    }
}

extern "C" void kernel_launch(void* const* d_in, const int* in_sizes, int n_in,
                              void* d_out, int out_size, void* d_ws, size_t ws_size,
                              hipStream_t stream) {
    const float* x     = (const float*)d_in[0];
    const float* Wemb  = (const float*)d_in[1];
    const float* bemb  = (const float*)d_in[2];
    const float* Wf    = (const float*)d_in[3];
    const float* bf_   = (const float*)d_in[4];
    const float* Wi    = (const float*)d_in[5];
    const float* bi_   = (const float*)d_in[6];
    const float* Wg    = (const float*)d_in[7];
    const float* bg_   = (const float*)d_in[8];
    const float* Wo    = (const float*)d_in[9];
    const float* bo_   = (const float*)d_in[10];
    const float* Wout  = (const float*)d_in[11];
    const float* bout  = (const float*)d_in[12];
    float* out = (float*)d_out;
    ushort* e_ws = (ushort*)d_ws;   // [T][B][24] bf16, 96 MB

    int nrows = BATCH * T_STEPS;                 // 2M rows
    emb_kernel<<<nrows / 256, 256, 0, stream>>>(x, Wemb, bemb, e_ws);
    lstm_kernel<<<BATCH / 16, 512, 0, stream>>>(e_ws, Wf, bf_, Wi, bi_, Wg, bg_,
                                                Wo, bo_, Wout, bout, out);
}

// Round 2
// 1748.347 us; speedup vs baseline: 1.2335x; 1.2335x over previous
//
#include <hip/hip_runtime.h>
#include <hip/hip_bf16.h>

#define T_STEPS 2048
#define BATCH   1024
#define NUNITS  128
#define EMB     24

typedef __attribute__((ext_vector_type(8))) __bf16 bf16x8;
typedef __attribute__((ext_vector_type(4))) __bf16 bf16x4;
typedef __attribute__((ext_vector_type(4))) float  f32x4;

__device__ __forceinline__ float sigm(float x) {
    // 1/(1+2^(-x*log2e))
    return __builtin_amdgcn_rcpf(1.0f + __builtin_amdgcn_exp2f(-1.4426950408889634f * x));
}
__device__ __forceinline__ float tanh_f(float x) {
    // 1 - 2/(1+2^(x*2*log2e));  x->+inf: exp->inf, rcp->0 -> 1;  x->-inf: exp->0 -> -1
    return fmaf(-2.0f, __builtin_amdgcn_rcpf(1.0f + __builtin_amdgcn_exp2f(2.8853900817779268f * x)), 1.0f);
}

// ---------------- embedding pre-pass: e[t][b][j] = sigmoid(x[b][t][:] @ Wemb + bemb), bf16 out
__global__ __launch_bounds__(256) void emb_kernel(const float* __restrict__ x,
                                                  const float* __restrict__ Wemb,
                                                  const float* __restrict__ bemb,
                                                  ushort* __restrict__ e_out) {
    int g = blockIdx.x * 256 + threadIdx.x;   // g = t*1024 + b
    int t = g >> 10;
    int b = g & 1023;
    const float* xr = x + ((size_t)b * T_STEPS + t) * 64;

    float4 xv[16];
#pragma unroll
    for (int i = 0; i < 16; i++) xv[i] = ((const float4*)xr)[i];

    float acc[24];
#pragma unroll
    for (int j = 0; j < 24; j++) acc[j] = bemb[j];

#pragma unroll
    for (int d = 0; d < 64; d++) {
        float xs = ((const float*)xv)[d];
#pragma unroll
        for (int j = 0; j < 24; j++) acc[j] = fmaf(xs, Wemb[d * 24 + j], acc[j]);
    }

    uint outp[12];
#pragma unroll
    for (int p = 0; p < 12; p++) {
        ushort lo = __builtin_bit_cast(ushort, (__bf16)sigm(acc[2 * p]));
        ushort hi = __builtin_bit_cast(ushort, (__bf16)sigm(acc[2 * p + 1]));
        outp[p] = (uint)lo | ((uint)hi << 16);
    }
    uint4* dst = (uint4*)(e_out + (size_t)g * 24);
#pragma unroll
    for (int q = 0; q < 3; q++) dst[q] = ((const uint4*)outp)[q];
}

// ---------------- recurrent kernel: 64 blocks x 512 threads, 16 batch rows per block
// Swapped-operand MFMA: A = W (registers), B = z (LDS/regs), D[m=unit][n=batchrow].
// Thread (wv,kg,l15) owns batch row l15, units 16*wv + 4*kg + {0..3}.
#define ZSTRIDE 136   // bf16 elems per z row (128 h + 8 pad for banking); 272 B
__global__ __launch_bounds__(512) void lstm_kernel(
    const ushort* __restrict__ e_ws,
    const float* __restrict__ Wf, const float* __restrict__ bf_,
    const float* __restrict__ Wi, const float* __restrict__ bi_,
    const float* __restrict__ Wg, const float* __restrict__ bg_,
    const float* __restrict__ Wo, const float* __restrict__ bo_,
    const float* __restrict__ Wout, const float* __restrict__ bout,
    float* __restrict__ out) {
    __shared__ __align__(16) __bf16 zbuf[2][16][ZSTRIDE];   // [buf][batchrow][unit k]

    const int tid  = threadIdx.x;
    const int lane = tid & 63;
    const int wv   = tid >> 6;      // wave 0..7 -> unit tile [16wv, 16wv+16)
    const int l15  = lane & 15;     // batch row within block / A-frag m index
    const int kg   = lane >> 4;     // 0..3 k-group
    const int r0   = blockIdx.x * 16;

    // ---- persistent W fragments (A operand): lane holds W[k = ks*32+kg*8+j][unit 16wv+l15]
    const float* Wp[4] = {Wf, Wi, Wg, Wo};
    const int ucol = wv * 16 + l15;
    bf16x8 wreg[4][5];
#pragma unroll
    for (int gt = 0; gt < 4; gt++) {
        const float* W = Wp[gt];
#pragma unroll
        for (int ks = 0; ks < 5; ks++) {
#pragma unroll
            for (int j = 0; j < 8; j++) {
                int k = ks * 32 + kg * 8 + j;
                float v = 0.0f;
                if (k < 128) v = W[(24 + k) * NUNITS + ucol];        // h part (ref rows 24..151)
                else if (k < 152) v = W[(k - 128) * NUNITS + ucol];  // e part (ref rows 0..23)
                wreg[gt][ks][j] = (__bf16)v;
            }
        }
    }
    // biases for this thread's 4 units (C-operand of first MFMA in each chain)
    const int u0 = wv * 16 + kg * 4;
    const f32x4 biasF = *(const f32x4*)(bf_ + u0);
    const f32x4 biasI = *(const f32x4*)(bi_ + u0);
    const f32x4 biasG = *(const f32x4*)(bg_ + u0);
    const f32x4 biasO = *(const f32x4*)(bo_ + u0);

    // zero both z buffers (h0 = 0)
    for (int i = tid; i < 2 * 16 * ZSTRIDE; i += 512) ((__bf16*)zbuf)[i] = (__bf16)0.0f;
    __syncthreads();

    // ---- e fragment prefetch ring, depth 2 (register-resident B-frag for ks=4)
    // lane (kg<3, l15) loads e[t][r0+l15][kg*8 .. +8]; kg==3 stays zero (W there is 0 anyway)
    const ushort* elbase = e_ws + ((size_t)(r0 + l15) * 24 + kg * 8);
    bf16x8 e0, e1;
#pragma unroll
    for (int j = 0; j < 8; j++) { e0[j] = (__bf16)0.0f; e1[j] = (__bf16)0.0f; }
    if (kg < 3) {
        e0 = *(const bf16x8*)(const void*)(elbase);
        e1 = *(const bf16x8*)(const void*)(elbase + 24576);   // t=1 (1024*24 elems/step)
    }

    float c[4] = {0, 0, 0, 0};
    float h[4];

    auto STEP = [&](int tcur, int P, bf16x8& ecur) {
        const __bf16* zb = &zbuf[P][0][0] + l15 * ZSTRIDE + kg * 8;
        bf16x8 z0 = *(const bf16x8*)(const void*)(zb);
        bf16x8 z1 = *(const bf16x8*)(const void*)(zb + 32);
        bf16x8 z2 = *(const bf16x8*)(const void*)(zb + 64);
        bf16x8 z3 = *(const bf16x8*)(const void*)(zb + 96);

        // ks=4 first (consumes ecur, injects bias), then reload ecur for t+2
        f32x4 aF = __builtin_amdgcn_mfma_f32_16x16x32_bf16(wreg[0][4], ecur, biasF, 0, 0, 0);
        f32x4 aI = __builtin_amdgcn_mfma_f32_16x16x32_bf16(wreg[1][4], ecur, biasI, 0, 0, 0);
        f32x4 aG = __builtin_amdgcn_mfma_f32_16x16x32_bf16(wreg[2][4], ecur, biasG, 0, 0, 0);
        f32x4 aO = __builtin_amdgcn_mfma_f32_16x16x32_bf16(wreg[3][4], ecur, biasO, 0, 0, 0);

        int tf = tcur + 2;
        if (tf > T_STEPS - 1) tf = T_STEPS - 1;   // clamped redundant load, value unused
        if (kg < 3) ecur = *(const bf16x8*)(const void*)(elbase + (size_t)tf * 24576);

        aF = __builtin_amdgcn_mfma_f32_16x16x32_bf16(wreg[0][0], z0, aF, 0, 0, 0);
        aI = __builtin_amdgcn_mfma_f32_16x16x32_bf16(wreg[1][0], z0, aI, 0, 0, 0);
        aG = __builtin_amdgcn_mfma_f32_16x16x32_bf16(wreg[2][0], z0, aG, 0, 0, 0);
        aO = __builtin_amdgcn_mfma_f32_16x16x32_bf16(wreg[3][0], z0, aO, 0, 0, 0);
        aF = __builtin_amdgcn_mfma_f32_16x16x32_bf16(wreg[0][1], z1, aF, 0, 0, 0);
        aI = __builtin_amdgcn_mfma_f32_16x16x32_bf16(wreg[1][1], z1, aI, 0, 0, 0);
        aG = __builtin_amdgcn_mfma_f32_16x16x32_bf16(wreg[2][1], z1, aG, 0, 0, 0);
        aO = __builtin_amdgcn_mfma_f32_16x16x32_bf16(wreg[3][1], z1, aO, 0, 0, 0);
        aF = __builtin_amdgcn_mfma_f32_16x16x32_bf16(wreg[0][2], z2, aF, 0, 0, 0);
        aI = __builtin_amdgcn_mfma_f32_16x16x32_bf16(wreg[1][2], z2, aI, 0, 0, 0);
        aG = __builtin_amdgcn_mfma_f32_16x16x32_bf16(wreg[2][2], z2, aG, 0, 0, 0);
        aO = __builtin_amdgcn_mfma_f32_16x16x32_bf16(wreg[3][2], z2, aO, 0, 0, 0);
        aF = __builtin_amdgcn_mfma_f32_16x16x32_bf16(wreg[0][3], z3, aF, 0, 0, 0);
        aI = __builtin_amdgcn_mfma_f32_16x16x32_bf16(wreg[1][3], z3, aI, 0, 0, 0);
        aG = __builtin_amdgcn_mfma_f32_16x16x32_bf16(wreg[2][3], z3, aG, 0, 0, 0);
        aO = __builtin_amdgcn_mfma_f32_16x16x32_bf16(wreg[3][3], z3, aO, 0, 0, 0);

        bf16x4 hp;
#pragma unroll
        for (int r = 0; r < 4; r++) {
            float fg = sigm(aF[r]);
            float ig = sigm(aI[r]);
            float gg = tanh_f(aG[r]);
            float og = sigm(aO[r]);
            c[r] = fmaf(c[r], fg, ig * gg);
            h[r] = tanh_f(c[r]) * og;
            hp[r] = (__bf16)h[r];
        }
        // h[batchrow=l15][units u0..u0+4) -> single b64, conflict-free
        *(bf16x4*)(&zbuf[P ^ 1][l15][u0]) = hp;

        // LDS-only drain + barrier: vmem e-prefetch stays in flight (no vmcnt drain)
        asm volatile("s_waitcnt lgkmcnt(0)" ::: "memory");
        __builtin_amdgcn_s_barrier();
        __builtin_amdgcn_sched_barrier(0);
    };

    for (int t = 0; t < T_STEPS; t += 2) {
        STEP(t, 0, e0);
        STEP(t + 1, 1, e1);
    }

    // h_last is in zbuf[0] (last step wrote P^1 = 0, barrier already done)
    if (tid < 16) {
        float s = bout[0];
        const __bf16* zr = &zbuf[0][tid][0];
#pragma unroll
        for (int k = 0; k < NUNITS; k++) s += (float)zr[k] * Wout[k];
        out[r0 + tid] = sigm(s);
    }
}

extern "C" void kernel_launch(void* const* d_in, const int* in_sizes, int n_in,
                              void* d_out, int out_size, void* d_ws, size_t ws_size,
                              hipStream_t stream) {
    const float* x     = (const float*)d_in[0];
    const float* Wemb  = (const float*)d_in[1];
    const float* bemb  = (const float*)d_in[2];
    const float* Wf    = (const float*)d_in[3];
    const float* bf_   = (const float*)d_in[4];
    const float* Wi    = (const float*)d_in[5];
    const float* bi_   = (const float*)d_in[6];
    const float* Wg    = (const float*)d_in[7];
    const float* bg_   = (const float*)d_in[8];
    const float* Wo    = (const float*)d_in[9];
    const float* bo_   = (const float*)d_in[10];
    const float* Wout  = (const float*)d_in[11];
    const float* bout  = (const float*)d_in[12];
    float* out = (float*)d_out;
    ushort* e_ws = (ushort*)d_ws;   // [T][B][24] bf16, ~96 MB

    int nrows = BATCH * T_STEPS;                 // 2M rows
    emb_kernel<<<nrows / 256, 256, 0, stream>>>(x, Wemb, bemb, e_ws);
    lstm_kernel<<<BATCH / 16, 512, 0, stream>>>(e_ws, Wf, bf_, Wi, bi_, Wg, bg_,
                                                Wo, bo_, Wout, bout, out);
}

// Round 3
// 1609.369 us; speedup vs baseline: 1.3400x; 1.0864x over previous
//
#include <hip/hip_runtime.h>
#include <hip/hip_bf16.h>

#define T_STEPS 2048
#define BATCH   1024
#define NUNITS  128
#define EMB     24
#define LOG2E   1.4426950408889634f

typedef __attribute__((ext_vector_type(8))) __bf16 bf16x8;
typedef __attribute__((ext_vector_type(4))) __bf16 bf16x4;
typedef __attribute__((ext_vector_type(4))) float  f32x4;

__device__ __forceinline__ float sigm_pre(float xs) {
    // xs is PRE-SCALED by log2e: sigm = 1/(1+2^-xs)
    return __builtin_amdgcn_rcpf(1.0f + __builtin_amdgcn_exp2f(-xs));
}
__device__ __forceinline__ float tanh_pre(float xs) {
    // xs PRE-SCALED by 2*log2e: tanh = 1 - 2/(1+2^xs); inf-safe (rcp(inf)=0)
    return fmaf(-2.0f, __builtin_amdgcn_rcpf(1.0f + __builtin_amdgcn_exp2f(xs)), 1.0f);
}

// ---------------- embedding pre-pass (HBM-bound, ~100us: at roof)
__global__ __launch_bounds__(256) void emb_kernel(const float* __restrict__ x,
                                                  const float* __restrict__ Wemb,
                                                  const float* __restrict__ bemb,
                                                  ushort* __restrict__ e_out) {
    int g = blockIdx.x * 256 + threadIdx.x;   // g = t*1024 + b
    int t = g >> 10;
    int b = g & 1023;
    const float* xr = x + ((size_t)b * T_STEPS + t) * 64;

    float4 xv[16];
#pragma unroll
    for (int i = 0; i < 16; i++) xv[i] = ((const float4*)xr)[i];

    float acc[24];
#pragma unroll
    for (int j = 0; j < 24; j++) acc[j] = bemb[j];

#pragma unroll
    for (int d = 0; d < 64; d++) {
        float xs = ((const float*)xv)[d];
#pragma unroll
        for (int j = 0; j < 24; j++) acc[j] = fmaf(xs, Wemb[d * 24 + j], acc[j]);
    }

    uint outp[12];
#pragma unroll
    for (int p = 0; p < 12; p++) {
        float lo = __builtin_amdgcn_rcpf(1.0f + __builtin_amdgcn_exp2f(-LOG2E * acc[2 * p]));
        float hi = __builtin_amdgcn_rcpf(1.0f + __builtin_amdgcn_exp2f(-LOG2E * acc[2 * p + 1]));
        ushort ulo = __builtin_bit_cast(ushort, (__bf16)lo);
        ushort uhi = __builtin_bit_cast(ushort, (__bf16)hi);
        outp[p] = (uint)ulo | ((uint)uhi << 16);
    }
    uint4* dst = (uint4*)(e_out + (size_t)g * 24);
#pragma unroll
    for (int q = 0; q < 3; q++) dst[q] = ((const uint4*)outp)[q];
}

// ---------------- recurrent kernel: 64 blocks x 512 threads, 16 batch rows per block
// Swapped-operand MFMA: A = W (regs), B = z (LDS frag-major), D[m=unit][n=batchrow].
// Thread (wv,kg,l15): batch row l15, units u0 = 16*wv + 4*kg + {0..3}.
// LDS layout (fragment-major): zfrag[P][ks][kg][row][j] -> wave reads 4 linear b128,
// h-store is one 8B write. Conflict-free both sides.
__global__ __launch_bounds__(512) void lstm_kernel(
    const ushort* __restrict__ e_ws,
    const float* __restrict__ Wf, const float* __restrict__ bf_,
    const float* __restrict__ Wi, const float* __restrict__ bi_,
    const float* __restrict__ Wg, const float* __restrict__ bg_,
    const float* __restrict__ Wo, const float* __restrict__ bo_,
    const float* __restrict__ Wout, const float* __restrict__ bout,
    float* __restrict__ out) {
    __shared__ __align__(16) __bf16 zfrag[2][4][4][16][8];   // 8 KiB

    const int tid  = threadIdx.x;
    const int lane = tid & 63;
    const int wv   = tid >> 6;      // wave 0..7 -> unit tile [16wv,16wv+16)
    const int l15  = lane & 15;     // batch row
    const int kg   = lane >> 4;     // k-group 0..3
    const int r0   = blockIdx.x * 16;

    // ---- persistent W fragments (A operand), pre-scaled by the exp2 constants
    const float* Wp[4] = {Wf, Wi, Wg, Wo};
    const float gsc[4] = {LOG2E, LOG2E, 2.0f * LOG2E, LOG2E};
    const int ucol = wv * 16 + l15;
    bf16x8 wreg[4][5];
#pragma unroll
    for (int gt = 0; gt < 4; gt++) {
        const float* W = Wp[gt];
#pragma unroll
        for (int ks = 0; ks < 5; ks++) {
#pragma unroll
            for (int j = 0; j < 8; j++) {
                int k = ks * 32 + kg * 8 + j;
                float v = 0.0f;
                if (k < 128) v = W[(24 + k) * NUNITS + ucol];        // h rows (ref 24..151)
                else if (k < 152) v = W[(k - 128) * NUNITS + ucol];  // e rows (ref 0..23)
                wreg[gt][ks][j] = (__bf16)(v * gsc[gt]);
            }
        }
    }
    const int u0 = wv * 16 + kg * 4;   // this thread's first unit
    f32x4 biasF, biasI, biasG, biasO;
#pragma unroll
    for (int r = 0; r < 4; r++) {
        biasF[r] = bf_[u0 + r] * LOG2E;
        biasI[r] = bi_[u0 + r] * LOG2E;
        biasG[r] = bg_[u0 + r] * 2.0f * LOG2E;
        biasO[r] = bo_[u0 + r] * LOG2E;
    }

    // zero both z buffers (h0 = 0)
    for (int i = tid; i < 2 * 4 * 4 * 16 * 8; i += 512) ((__bf16*)zfrag)[i] = (__bf16)0.0f;

    // read base (per wave identical across wv): &zfrag[P][0][kg][l15][0], + ks*512 elems
    const __bf16* zrd = &zfrag[0][0][kg][l15][0];
    // write slot for this thread's 4 units (8B)
    __bf16* zwr = &zfrag[0][u0 >> 5][(u0 >> 3) & 3][l15][u0 & 7];
    const int PSTRIDE = 4 * 4 * 16 * 8;   // elems per buffer

    // ---- e prefetch ring, depth 2
    const ushort* elbase = e_ws + ((size_t)(r0 + l15) * 24 + kg * 8);
    bf16x8 e0, e1;
#pragma unroll
    for (int j = 0; j < 8; j++) { e0[j] = (__bf16)0.0f; e1[j] = (__bf16)0.0f; }
    if (kg < 3) {
        e0 = *(const bf16x8*)(const void*)(elbase);
        e1 = *(const bf16x8*)(const void*)(elbase + 24576);
    }

    __syncthreads();

    float c[4] = {0, 0, 0, 0};
    // eacc = bias + W_e * e(t), computed one step ahead (independent of h)
    f32x4 eaF, eaI, eaG, eaO, ebF, ebI, ebG, ebO;
    eaF = __builtin_amdgcn_mfma_f32_16x16x32_bf16(wreg[0][4], e0, biasF, 0, 0, 0);
    eaI = __builtin_amdgcn_mfma_f32_16x16x32_bf16(wreg[1][4], e0, biasI, 0, 0, 0);
    eaG = __builtin_amdgcn_mfma_f32_16x16x32_bf16(wreg[2][4], e0, biasG, 0, 0, 0);
    eaO = __builtin_amdgcn_mfma_f32_16x16x32_bf16(wreg[3][4], e0, biasO, 0, 0, 0);
    if (kg < 3) e0 = *(const bf16x8*)(const void*)(elbase + 2 * 24576);   // e(2)

    auto STEP = [&](int t, int P, f32x4& cF, f32x4& cI, f32x4& cG, f32x4& cO,
                    f32x4& nF, f32x4& nI, f32x4& nG, f32x4& nO, bf16x8& enext) {
        // z reads: 4 linear b128 (per-wave contiguous 1KiB region)
        const __bf16* zb = zrd + P * PSTRIDE;
        bf16x8 z0 = *(const bf16x8*)(const void*)(zb);
        bf16x8 z1 = *(const bf16x8*)(const void*)(zb + 512);
        bf16x8 z2 = *(const bf16x8*)(const void*)(zb + 1024);
        bf16x8 z3 = *(const bf16x8*)(const void*)(zb + 1536);

        f32x4 aF = cF, aI = cI, aG = cG, aO = cO;
        aF = __builtin_amdgcn_mfma_f32_16x16x32_bf16(wreg[0][0], z0, aF, 0, 0, 0);
        aI = __builtin_amdgcn_mfma_f32_16x16x32_bf16(wreg[1][0], z0, aI, 0, 0, 0);
        aG = __builtin_amdgcn_mfma_f32_16x16x32_bf16(wreg[2][0], z0, aG, 0, 0, 0);
        aO = __builtin_amdgcn_mfma_f32_16x16x32_bf16(wreg[3][0], z0, aO, 0, 0, 0);
        aF = __builtin_amdgcn_mfma_f32_16x16x32_bf16(wreg[0][1], z1, aF, 0, 0, 0);
        aI = __builtin_amdgcn_mfma_f32_16x16x32_bf16(wreg[1][1], z1, aI, 0, 0, 0);
        aG = __builtin_amdgcn_mfma_f32_16x16x32_bf16(wreg[2][1], z1, aG, 0, 0, 0);
        aO = __builtin_amdgcn_mfma_f32_16x16x32_bf16(wreg[3][1], z1, aO, 0, 0, 0);
        aF = __builtin_amdgcn_mfma_f32_16x16x32_bf16(wreg[0][2], z2, aF, 0, 0, 0);
        aI = __builtin_amdgcn_mfma_f32_16x16x32_bf16(wreg[1][2], z2, aI, 0, 0, 0);
        aG = __builtin_amdgcn_mfma_f32_16x16x32_bf16(wreg[2][2], z2, aG, 0, 0, 0);
        aO = __builtin_amdgcn_mfma_f32_16x16x32_bf16(wreg[3][2], z2, aO, 0, 0, 0);
        aF = __builtin_amdgcn_mfma_f32_16x16x32_bf16(wreg[0][3], z3, aF, 0, 0, 0);
        aI = __builtin_amdgcn_mfma_f32_16x16x32_bf16(wreg[1][3], z3, aI, 0, 0, 0);
        aG = __builtin_amdgcn_mfma_f32_16x16x32_bf16(wreg[2][3], z3, aG, 0, 0, 0);
        aO = __builtin_amdgcn_mfma_f32_16x16x32_bf16(wreg[3][3], z3, aO, 0, 0, 0);

        // hoisted e-MFMAs for step t+1 (independent of h; fill MFMA pipe during VALU)
        nF = __builtin_amdgcn_mfma_f32_16x16x32_bf16(wreg[0][4], enext, biasF, 0, 0, 0);
        nI = __builtin_amdgcn_mfma_f32_16x16x32_bf16(wreg[1][4], enext, biasI, 0, 0, 0);
        nG = __builtin_amdgcn_mfma_f32_16x16x32_bf16(wreg[2][4], enext, biasG, 0, 0, 0);
        nO = __builtin_amdgcn_mfma_f32_16x16x32_bf16(wreg[3][4], enext, biasO, 0, 0, 0);
        // refill enext with e(t+3), clamped
        {
            int tf = t + 3; if (tf > T_STEPS - 1) tf = T_STEPS - 1;
            if (kg < 3) enext = *(const bf16x8*)(const void*)(elbase + (size_t)tf * 24576);
        }

        bf16x4 hp;
#pragma unroll
        for (int r = 0; r < 4; r++) {
            float fg = sigm_pre(aF[r]);
            float ig = sigm_pre(aI[r]);
            float gg = tanh_pre(aG[r]);
            float og = sigm_pre(aO[r]);
            c[r] = fmaf(c[r], fg, ig * gg);
            float th = tanh_pre(2.0f * LOG2E * c[r]);
            hp[r] = (__bf16)(th * og);
        }
        *(bf16x4*)(zwr + (P ^ 1) * PSTRIDE) = hp;

        // LDS-only drain + barrier: vmem e-prefetch stays in flight
        asm volatile("s_waitcnt lgkmcnt(0)" ::: "memory");
        __builtin_amdgcn_s_barrier();
        __builtin_amdgcn_sched_barrier(0);
    };

    for (int t = 0; t < T_STEPS; t += 2) {
        STEP(t,     0, eaF, eaI, eaG, eaO, ebF, ebI, ebG, ebO, e1);
        STEP(t + 1, 1, ebF, ebI, ebG, ebO, eaF, eaI, eaG, eaO, e0);
    }

    // h_last is in zfrag[0]
    if (tid < 16) {
        float s = bout[0];
#pragma unroll
        for (int k = 0; k < NUNITS; k++) {
            float hv = (float)zfrag[0][k >> 5][(k >> 3) & 3][tid][k & 7];
            s += hv * Wout[k];
        }
        out[r0 + tid] = __builtin_amdgcn_rcpf(1.0f + __builtin_amdgcn_exp2f(-LOG2E * s));
    }
}

extern "C" void kernel_launch(void* const* d_in, const int* in_sizes, int n_in,
                              void* d_out, int out_size, void* d_ws, size_t ws_size,
                              hipStream_t stream) {
    const float* x     = (const float*)d_in[0];
    const float* Wemb  = (const float*)d_in[1];
    const float* bemb  = (const float*)d_in[2];
    const float* Wf    = (const float*)d_in[3];
    const float* bf_   = (const float*)d_in[4];
    const float* Wi    = (const float*)d_in[5];
    const float* bi_   = (const float*)d_in[6];
    const float* Wg    = (const float*)d_in[7];
    const float* bg_   = (const float*)d_in[8];
    const float* Wo    = (const float*)d_in[9];
    const float* bo_   = (const float*)d_in[10];
    const float* Wout  = (const float*)d_in[11];
    const float* bout  = (const float*)d_in[12];
    float* out = (float*)d_out;
    ushort* e_ws = (ushort*)d_ws;   // [T][B][24] bf16, ~96 MB

    int nrows = BATCH * T_STEPS;
    emb_kernel<<<nrows / 256, 256, 0, stream>>>(x, Wemb, bemb, e_ws);
    lstm_kernel<<<BATCH / 16, 512, 0, stream>>>(e_ws, Wf, bf_, Wi, bi_, Wg, bg_,
                                                Wo, bo_, Wout, bout, out);
}